// Round 1
// baseline (2372.158 us; speedup 1.0000x reference)
//
#include <hip/hip_runtime.h>
#include <hip/hip_bf16.h>
#include <math.h>

// ---------------------------------------------------------------------------
// GATv2 x2 + Linear fused pipeline, fp32.
// Reference: GATv2Conv(heads=8,C=16,concat) -> ELU -> GATv2Conv(1,64) -> ELU
//            -> Linear(64,128) -> ELU
// ---------------------------------------------------------------------------

#define NEG_SLOPE 0.2f

__device__ __forceinline__ unsigned int enc_f32(float f) {
    unsigned int u = __float_as_uint(f);
    return (u & 0x80000000u) ? ~u : (u | 0x80000000u);
}
__device__ __forceinline__ float dec_f32(unsigned int u) {
    return (u & 0x80000000u) ? __uint_as_float(u ^ 0x80000000u)
                             : __uint_as_float(~u);
}

// --- edge-index dtype detection (int32 vs int64) ---------------------------
// If data is int64 (little-endian), every odd 32-bit word is a zero high-half
// (values in [0, 50000)). If int32, odd words are real src values (~never all 0).
__global__ __launch_bounds__(256) void detect_kernel(const int* __restrict__ ei,
                                                     int* __restrict__ flag,
                                                     int twoE) {
    __shared__ int any;
    if (threadIdx.x == 0) any = 0;
    __syncthreads();
    int idx = 2 * (int)threadIdx.x + 1;
    if (idx < twoE && ei[idx] != 0) atomicOr(&any, 1);
    __syncthreads();
    if (threadIdx.x == 0) *flag = any;   // 1 => int32, 0 => int64
}

__global__ __launch_bounds__(256) void convert_edges(const int* __restrict__ ei,
                                                     const int* __restrict__ flag,
                                                     int* __restrict__ srcA,
                                                     int* __restrict__ dstA,
                                                     int E, int Et) {
    int e = blockIdx.x * 256 + threadIdx.x;
    if (e >= Et) return;
    int s, d;
    if (e < E) {
        if (*flag) { s = ei[e];      d = ei[E + e]; }          // int32 layout
        else       { s = ei[2 * e];  d = ei[2 * (E + e)]; }    // int64 low words
    } else {
        s = d = e - E;  // self loop
    }
    srcA[e] = s;
    dstA[e] = d;
}

// --- generic GEMM: Y[N,M] = act(X[N,K] @ W[K,M] + bias) --------------------
// blockDim.x == M (64 or 128). 64 rows per block, staged 8 at a time.
__global__ __launch_bounds__(128) void gemm_kernel(const float* __restrict__ X,
                                                   const float* __restrict__ W,
                                                   const float* __restrict__ bias,
                                                   float* __restrict__ Y,
                                                   int N, int K, int M, int act) {
    extern __shared__ float lds[];
    float* Wl = lds;            // K*M
    float* Xs = lds + (size_t)K * M;  // 8*K
    int col = threadIdx.x;
    for (int i = col; i < K * M; i += blockDim.x) Wl[i] = W[i];
    __syncthreads();
    int row0 = blockIdx.x * 64;
    float bcol = bias[col];
    for (int rb = 0; rb < 64; rb += 8) {
        int base = row0 + rb;
        for (int i = col; i < 8 * K; i += blockDim.x) {
            int r = i / K, k = i - r * K;
            int gr = base + r;
            Xs[i] = (gr < N) ? X[(size_t)gr * K + k] : 0.f;
        }
        __syncthreads();
        for (int r = 0; r < 8; ++r) {
            int gr = base + r;
            if (gr < N) {
                const float* xs = &Xs[r * K];
                float acc = 0.f;
                #pragma unroll 8
                for (int k = 0; k < K; ++k) acc += xs[k] * Wl[k * M + col];
                acc += bcol;
                if (act == 1) acc = acc > 0.f ? acc : expm1f(acc);
                Y[(size_t)gr * M + col] = acc;
            }
        }
        __syncthreads();
    }
}

// --- edge scores + segment max ---------------------------------------------
// H*C threads per edge; thread i handles head h=i/C channel c=i%C.
template <int H, int C>
__global__ __launch_bounds__(256) void score_kernel(const float* __restrict__ xl,
                                                    const float* __restrict__ xr,
                                                    const int* __restrict__ srcA,
                                                    const int* __restrict__ dstA,
                                                    const float* __restrict__ att,
                                                    float* __restrict__ logits,
                                                    unsigned int* __restrict__ m,
                                                    int Et) {
    constexpr int HC = H * C;
    constexpr int EPB = 256 / HC;
    int t = threadIdx.x;
    int e = blockIdx.x * EPB + t / HC;
    int i = t % HC;
    if (e >= Et) return;
    int s = srcA[e], d = dstA[e];
    float v = xl[(size_t)s * HC + i] + xr[(size_t)d * HC + i];
    v = v > 0.f ? v : NEG_SLOPE * v;
    v *= att[i];
    #pragma unroll
    for (int off = C / 2; off > 0; off >>= 1) v += __shfl_down(v, off, C);
    if ((i % C) == 0) {
        int h = i / C;
        logits[(size_t)e * H + h] = v;
        atomicMax(&m[(size_t)d * H + h], enc_f32(v));
    }
}

// --- exp + denom + unnormalized aggregate ----------------------------------
template <int H, int C>
__global__ __launch_bounds__(256) void expagg_kernel(const float* __restrict__ xl,
                                                     const int* __restrict__ srcA,
                                                     const int* __restrict__ dstA,
                                                     const float* __restrict__ logits,
                                                     const unsigned int* __restrict__ m,
                                                     float* __restrict__ denom,
                                                     float* __restrict__ agg,
                                                     int Et) {
    constexpr int HC = H * C;
    constexpr int EPB = 256 / HC;
    int t = threadIdx.x;
    int e = blockIdx.x * EPB + t / HC;
    int i = t % HC;
    if (e >= Et) return;
    int s = srcA[e], d = dstA[e];
    int h = i / C;
    float mv = dec_f32(m[(size_t)d * H + h]);
    float ex = expf(logits[(size_t)e * H + h] - mv);
    if ((i % C) == 0) atomicAdd(&denom[(size_t)d * H + h], ex);
    atomicAdd(&agg[(size_t)d * HC + i], ex * xl[(size_t)s * HC + i]);
}

// --- finalize: out = elu(agg/denom + bias) ---------------------------------
__global__ __launch_bounds__(256) void finalize_kernel(float* __restrict__ agg,
                                                       const float* __restrict__ denom,
                                                       const float* __restrict__ bias,
                                                       int N, int H, int C) {
    int idx = blockIdx.x * 256 + threadIdx.x;
    int HC = H * C;
    if (idx >= N * HC) return;
    int i = idx % HC;
    int n = idx / HC;
    int h = i / C;
    float v = agg[idx] / denom[(size_t)n * H + h] + bias[i];
    agg[idx] = v > 0.f ? v : expm1f(v);
}

extern "C" void kernel_launch(void* const* d_in, const int* in_sizes, int n_in,
                              void* d_out, int out_size, void* d_ws, size_t ws_size,
                              hipStream_t stream) {
    const float* x    = (const float*)d_in[0];
    const int*   ei   = (const int*)d_in[1];
    const float* Wl1  = (const float*)d_in[2];
    const float* bl1  = (const float*)d_in[3];
    const float* Wr1  = (const float*)d_in[4];
    const float* br1  = (const float*)d_in[5];
    const float* att1 = (const float*)d_in[6];
    const float* bias1= (const float*)d_in[7];
    const float* Wl2  = (const float*)d_in[8];
    const float* bl2  = (const float*)d_in[9];
    const float* Wr2  = (const float*)d_in[10];
    const float* br2  = (const float*)d_in[11];
    const float* att2 = (const float*)d_in[12];
    const float* bias2= (const float*)d_in[13];
    const float* Wlin = (const float*)d_in[14];
    const float* blin = (const float*)d_in[15];
    float* out = (float*)d_out;

    const int F = 128;
    int N  = in_sizes[0] / F;        // 50000
    int E  = in_sizes[1] / 2;        // 800000
    int Et = E + N;                  // + self loops

    // workspace layout (all 4-byte elements)
    size_t nA = (size_t)N * 128;     // xl/xr/agg layer1 size
    size_t nC = (size_t)Et * 8;      // logits
    size_t nD = (size_t)N * 8;       // m / denom
    float*        A  = (float*)d_ws;          // xl1, then xl2
    float*        Bv = A + nA;                // xr1, then xr2
    float*        Cv = Bv + nA;               // logits1 / logits2
    unsigned int* Dm = (unsigned int*)(Cv + nC); // m
    float*        Ev = (float*)(Dm + nD);     // denom
    float*        Fv = Ev + nD;               // agg1/h1, then agg2/h2
    int*          Sv = (int*)(Fv + nA);       // src (int32, incl. self loops)
    int*          Tv = Sv + Et;               // dst
    int*          fl = Tv + Et;               // dtype flag

    auto cdiv = [](long a, long b) { return (int)((a + b - 1) / b); };
    int gemm_blocks = cdiv(N, 64);

    // edge normalization
    detect_kernel<<<1, 256, 0, stream>>>(ei, fl, 2 * E);
    convert_edges<<<cdiv(Et, 256), 256, 0, stream>>>(ei, fl, Sv, Tv, E, Et);

    // ---- layer 1 (H=8, C=16) ----
    gemm_kernel<<<gemm_blocks, 128, (128 * 128 + 8 * 128) * 4, stream>>>(
        x, Wl1, bl1, A, N, 128, 128, 0);
    gemm_kernel<<<gemm_blocks, 128, (128 * 128 + 8 * 128) * 4, stream>>>(
        x, Wr1, br1, Bv, N, 128, 128, 0);
    hipMemsetAsync(Dm, 0, (2 * nD + nA) * 4, stream);  // m, denom, agg
    score_kernel<8, 16><<<cdiv(Et, 2), 256, 0, stream>>>(A, Bv, Sv, Tv, att1, Cv, Dm, Et);
    expagg_kernel<8, 16><<<cdiv(Et, 2), 256, 0, stream>>>(A, Sv, Tv, Cv, Dm, Ev, Fv, Et);
    finalize_kernel<<<cdiv((long)N * 128, 256), 256, 0, stream>>>(Fv, Ev, bias1, N, 8, 16);

    // ---- layer 2 (H=1, C=64) ----
    gemm_kernel<<<gemm_blocks, 64, (128 * 64 + 8 * 128) * 4, stream>>>(
        Fv, Wl2, bl2, A, N, 128, 64, 0);
    gemm_kernel<<<gemm_blocks, 64, (128 * 64 + 8 * 128) * 4, stream>>>(
        Fv, Wr2, br2, Bv, N, 128, 64, 0);
    hipMemsetAsync(Dm, 0, (2 * nD + nA) * 4, stream);  // m, denom, agg (oversized, fine)
    score_kernel<1, 64><<<cdiv(Et, 4), 256, 0, stream>>>(A, Bv, Sv, Tv, att2, Cv, Dm, Et);
    expagg_kernel<1, 64><<<cdiv(Et, 4), 256, 0, stream>>>(A, Sv, Tv, Cv, Dm, Ev, Fv, Et);
    finalize_kernel<<<cdiv((long)N * 64, 256), 256, 0, stream>>>(Fv, Ev, bias2, N, 1, 64);

    // ---- final linear + ELU -> d_out ----
    gemm_kernel<<<gemm_blocks, 128, (64 * 128 + 8 * 64) * 4, stream>>>(
        Fv, Wlin, blin, out, N, 64, 128, 1);
}

// Round 2
// 1467.425 us; speedup vs baseline: 1.6165x; 1.6165x over previous
//
#include <hip/hip_runtime.h>
#include <hip/hip_bf16.h>
#include <math.h>

// ---------------------------------------------------------------------------
// GATv2 x2 + Linear, fp32. CSR-sorted edges + fused online-softmax aggregate
// (score + segment-max + exp + denom + aggregate + bias + ELU in one kernel,
// zero float atomics).
// ---------------------------------------------------------------------------

#define NEG_SLOPE 0.2f
#define CHUNK 2048

// --- edge-index dtype detection (int32 vs int64) ---------------------------
__global__ __launch_bounds__(256) void detect_kernel(const int* __restrict__ ei,
                                                     int* __restrict__ flag,
                                                     int twoE) {
    __shared__ int any;
    if (threadIdx.x == 0) any = 0;
    __syncthreads();
    int idx = 2 * (int)threadIdx.x + 1;
    if (idx < twoE && ei[idx] != 0) atomicOr(&any, 1);
    __syncthreads();
    if (threadIdx.x == 0) *flag = any;   // 1 => int32, 0 => int64
}

__global__ __launch_bounds__(256) void convert_edges(const int* __restrict__ ei,
                                                     const int* __restrict__ flag,
                                                     int* __restrict__ srcA,
                                                     int* __restrict__ dstA,
                                                     int E, int Et) {
    int e = blockIdx.x * 256 + threadIdx.x;
    if (e >= Et) return;
    int s, d;
    if (e < E) {
        if (*flag) { s = ei[e];      d = ei[E + e]; }          // int32 layout
        else       { s = ei[2 * e];  d = ei[2 * (E + e)]; }    // int64 low words
    } else {
        s = d = e - E;  // self loop
    }
    srcA[e] = s;
    dstA[e] = d;
}

// --- CSR build -------------------------------------------------------------
__global__ __launch_bounds__(256) void count_deg(const int* __restrict__ dstA,
                                                 int* __restrict__ deg, int Et) {
    int e = blockIdx.x * 256 + threadIdx.x;
    if (e < Et) atomicAdd(&deg[dstA[e]], 1);
}

// per-chunk exclusive scan (2048 elems/block), chunk totals to bsum
__global__ __launch_bounds__(256) void scan1(const int* __restrict__ deg,
                                             int* __restrict__ rowptr,
                                             int* __restrict__ bsum, int N) {
    __shared__ int tsum[256];
    int chunk0 = blockIdx.x * CHUNK;
    int t = threadIdx.x;
    int vals[8];
    int s = 0;
    #pragma unroll
    for (int i = 0; i < 8; ++i) {
        int idx = chunk0 + t * 8 + i;
        int v = (idx < N) ? deg[idx] : 0;
        vals[i] = s;
        s += v;
    }
    tsum[t] = s;
    __syncthreads();
    for (int off = 1; off < 256; off <<= 1) {
        int v = (t >= off) ? tsum[t - off] : 0;
        __syncthreads();
        tsum[t] += v;
        __syncthreads();
    }
    int texcl = (t > 0) ? tsum[t - 1] : 0;
    #pragma unroll
    for (int i = 0; i < 8; ++i) {
        int idx = chunk0 + t * 8 + i;
        if (idx < N) rowptr[idx] = texcl + vals[i];
    }
    if (t == 255) bsum[blockIdx.x] = tsum[255];
}

__global__ void scan2(int* __restrict__ bsum, int* __restrict__ rowptr,
                      int NB, int N) {
    if (threadIdx.x == 0 && blockIdx.x == 0) {
        int s = 0;
        for (int b = 0; b < NB; ++b) { int v = bsum[b]; bsum[b] = s; s += v; }
        rowptr[N] = s;
    }
}

__global__ __launch_bounds__(256) void scan3(int* __restrict__ rowptr,
                                             const int* __restrict__ bsum,
                                             int* __restrict__ cursor, int N) {
    int idx = blockIdx.x * 256 + threadIdx.x;
    if (idx < N) {
        int v = rowptr[idx] + bsum[idx / CHUNK];
        rowptr[idx] = v;
        cursor[idx] = v;
    }
}

__global__ __launch_bounds__(256) void scatter_edges(const int* __restrict__ srcA,
                                                     const int* __restrict__ dstA,
                                                     int* __restrict__ cursor,
                                                     int* __restrict__ csr_src,
                                                     int Et) {
    int e = blockIdx.x * 256 + threadIdx.x;
    if (e < Et) {
        int pos = atomicAdd(&cursor[dstA[e]], 1);
        csr_src[pos] = srcA[e];
    }
}

// --- generic GEMM: Y[N,M] = act(X[N,K] @ W[K,M] + bias) --------------------
__global__ __launch_bounds__(128) void gemm_kernel(const float* __restrict__ X,
                                                   const float* __restrict__ W,
                                                   const float* __restrict__ bias,
                                                   float* __restrict__ Y,
                                                   int N, int K, int M, int act) {
    extern __shared__ float lds[];
    float* Wl = lds;
    float* Xs = lds + (size_t)K * M;
    int col = threadIdx.x;
    for (int i = col; i < K * M; i += blockDim.x) Wl[i] = W[i];
    __syncthreads();
    int row0 = blockIdx.x * 64;
    float bcol = bias[col];
    for (int rb = 0; rb < 64; rb += 8) {
        int base = row0 + rb;
        for (int i = col; i < 8 * K; i += blockDim.x) {
            int r = i / K, k = i - r * K;
            int gr = base + r;
            Xs[i] = (gr < N) ? X[(size_t)gr * K + k] : 0.f;
        }
        __syncthreads();
        for (int r = 0; r < 8; ++r) {
            int gr = base + r;
            if (gr < N) {
                const float* xs = &Xs[r * K];
                float acc = 0.f;
                #pragma unroll 8
                for (int k = 0; k < K; ++k) acc += xs[k] * Wl[k * M + col];
                acc += bcol;
                if (act == 1) acc = acc > 0.f ? acc : expm1f(acc);
                Y[(size_t)gr * M + col] = acc;
            }
        }
        __syncthreads();
    }
}

// --- fused GATv2 aggregate: online softmax over CSR in-edges ---------------
// One wave per node. Lane handles CPL consecutive channels (c0 = lane*CPL).
// For CPL=2 (H=8,C=16): both channels in head lane/8 -> 8-lane head groups.
// For CPL=1 (H=1,C=64): whole wave is one head.
// Fuses bias + ELU epilogue.
template <int H, int C>
__global__ __launch_bounds__(256) void gat_agg(const float* __restrict__ xl,
                                               const float* __restrict__ xr,
                                               const float* __restrict__ att,
                                               const int* __restrict__ rowptr,
                                               const int* __restrict__ csr_src,
                                               const float* __restrict__ bias,
                                               float* __restrict__ outv,
                                               int N) {
    constexpr int HC  = H * C;
    constexpr int CPL = HC / 64;   // 2 for layer1, 1 for layer2
    constexpr int G   = C / CPL;   // lanes per head group (8 or 64)
    int wave = threadIdx.x >> 6;
    int lane = threadIdx.x & 63;
    int node = blockIdx.x * 4 + wave;
    if (node >= N) return;
    int c0 = lane * CPL;

    float a0 = att[c0];
    float xr0 = xr[(size_t)node * HC + c0];
    float a1 = 0.f, xr1v = 0.f;
    if constexpr (CPL == 2) {
        a1 = att[c0 + 1];
        xr1v = xr[(size_t)node * HC + c0 + 1];
    }

    float m = -INFINITY, dsum = 0.f, acc0 = 0.f, acc1 = 0.f;
    int start = rowptr[node], end = rowptr[node + 1];

    for (int base = start; base < end; base += 64) {
        int nbatch = min(64, end - base);
        int sreg = (base + lane < end) ? csr_src[base + lane] : 0;
        for (int k = 0; k < nbatch; ++k) {
            int s = __shfl(sreg, k, 64);
            float x0, x1v = 0.f;
            if constexpr (CPL == 2) {
                float2 xv = *(const float2*)&xl[(size_t)s * HC + c0];
                x0 = xv.x; x1v = xv.y;
            } else {
                x0 = xl[(size_t)s * HC + c0];
            }
            float t0 = x0 + xr0;
            t0 = t0 > 0.f ? t0 : NEG_SLOPE * t0;
            float part = t0 * a0;
            if constexpr (CPL == 2) {
                float t1 = x1v + xr1v;
                t1 = t1 > 0.f ? t1 : NEG_SLOPE * t1;
                part += t1 * a1;
            }
            #pragma unroll
            for (int off = 1; off < G; off <<= 1)
                part += __shfl_xor(part, off, 64);
            // part = logit for this lane's head (uniform within head group)
            float mnew = fmaxf(m, part);
            float alpha = __expf(m - mnew);   // 0 on first edge (m=-inf)
            float p = __expf(part - mnew);
            dsum = dsum * alpha + p;
            acc0 = acc0 * alpha + p * x0;
            if constexpr (CPL == 2) acc1 = acc1 * alpha + p * x1v;
            m = mnew;
        }
    }

    float inv = 1.f / dsum;   // deg >= 1 guaranteed by self-loops
    float v0 = acc0 * inv + bias[c0];
    v0 = v0 > 0.f ? v0 : expm1f(v0);
    outv[(size_t)node * HC + c0] = v0;
    if constexpr (CPL == 2) {
        float v1 = acc1 * inv + bias[c0 + 1];
        v1 = v1 > 0.f ? v1 : expm1f(v1);
        outv[(size_t)node * HC + c0 + 1] = v1;
    }
}

extern "C" void kernel_launch(void* const* d_in, const int* in_sizes, int n_in,
                              void* d_out, int out_size, void* d_ws, size_t ws_size,
                              hipStream_t stream) {
    const float* x    = (const float*)d_in[0];
    const int*   ei   = (const int*)d_in[1];
    const float* Wl1  = (const float*)d_in[2];
    const float* bl1  = (const float*)d_in[3];
    const float* Wr1  = (const float*)d_in[4];
    const float* br1  = (const float*)d_in[5];
    const float* att1 = (const float*)d_in[6];
    const float* bias1= (const float*)d_in[7];
    const float* Wl2  = (const float*)d_in[8];
    const float* bl2  = (const float*)d_in[9];
    const float* Wr2  = (const float*)d_in[10];
    const float* br2  = (const float*)d_in[11];
    const float* att2 = (const float*)d_in[12];
    const float* bias2= (const float*)d_in[13];
    const float* Wlin = (const float*)d_in[14];
    const float* blin = (const float*)d_in[15];
    float* out = (float*)d_out;

    const int F = 128;
    int N  = in_sizes[0] / F;        // 50000
    int E  = in_sizes[1] / 2;        // 800000
    int Et = E + N;                  // + self loops

    // workspace layout
    float* xl1 = (float*)d_ws;            // N*128; reused: xl2, xr2 (N*64 each)
    float* xr1 = xl1 + (size_t)N * 128;   // N*128; reused: h2 (N*64)
    float* h1  = xr1 + (size_t)N * 128;   // N*128
    int* srcA   = (int*)(h1 + (size_t)N * 128);
    int* dstA   = srcA + Et;
    int* deg    = dstA + Et;              // N
    int* rowptr = deg + N;                // N+1
    int* cursor = rowptr + N + 1;         // N
    int* csr_src= cursor + N;             // Et
    int* fl     = csr_src + Et;
    int* bsum   = fl + 1;                 // <=32

    float* xl2 = xl1;
    float* xr2 = xl1 + (size_t)N * 64;
    float* h2  = xr1;

    auto cdiv = [](long a, long b) { return (int)((a + b - 1) / b); };
    int gemm_blocks = cdiv(N, 64);
    int NB = cdiv(N, CHUNK);

    // edge normalization + CSR build (shared by both layers)
    detect_kernel<<<1, 256, 0, stream>>>(ei, fl, 2 * E);
    convert_edges<<<cdiv(Et, 256), 256, 0, stream>>>(ei, fl, srcA, dstA, E, Et);
    hipMemsetAsync(deg, 0, (size_t)N * 4, stream);
    count_deg<<<cdiv(Et, 256), 256, 0, stream>>>(dstA, deg, Et);
    scan1<<<NB, 256, 0, stream>>>(deg, rowptr, bsum, N);
    scan2<<<1, 64, 0, stream>>>(bsum, rowptr, NB, N);
    scan3<<<cdiv(N, 256), 256, 0, stream>>>(rowptr, bsum, cursor, N);
    scatter_edges<<<cdiv(Et, 256), 256, 0, stream>>>(srcA, dstA, cursor, csr_src, Et);

    // ---- layer 1 (H=8, C=16, concat) ----
    gemm_kernel<<<gemm_blocks, 128, (128 * 128 + 8 * 128) * 4, stream>>>(
        x, Wl1, bl1, xl1, N, 128, 128, 0);
    gemm_kernel<<<gemm_blocks, 128, (128 * 128 + 8 * 128) * 4, stream>>>(
        x, Wr1, br1, xr1, N, 128, 128, 0);
    gat_agg<8, 16><<<cdiv(N, 4), 256, 0, stream>>>(
        xl1, xr1, att1, rowptr, csr_src, bias1, h1, N);

    // ---- layer 2 (H=1, C=64) ----
    gemm_kernel<<<gemm_blocks, 64, (128 * 64 + 8 * 128) * 4, stream>>>(
        h1, Wl2, bl2, xl2, N, 128, 64, 0);
    gemm_kernel<<<gemm_blocks, 64, (128 * 64 + 8 * 128) * 4, stream>>>(
        h1, Wr2, br2, xr2, N, 128, 64, 0);
    gat_agg<1, 64><<<cdiv(N, 4), 256, 0, stream>>>(
        xl2, xr2, att2, rowptr, csr_src, bias2, h2, N);

    // ---- final linear + ELU -> d_out ----
    gemm_kernel<<<gemm_blocks, 128, (64 * 128 + 8 * 64) * 4, stream>>>(
        h2, Wlin, blin, out, N, 64, 128, 1);
}

// Round 3
// 507.075 us; speedup vs baseline: 4.6781x; 2.8939x over previous
//
#include <hip/hip_runtime.h>
#include <hip/hip_bf16.h>
#include <math.h>

// ---------------------------------------------------------------------------
// GATv2 x2 + Linear, fp32. CSR + fused online-softmax aggregate.
// Round 3: register-tiled GEMM (8x8 acc/thread) replacing the LDS-latency-
// bound naive GEMM (345us -> ~20us per GEMM expected).
// ---------------------------------------------------------------------------

#define NEG_SLOPE 0.2f
#define CHUNK 2048

// --- edge-index dtype detection (int32 vs int64) ---------------------------
__global__ __launch_bounds__(256) void detect_kernel(const int* __restrict__ ei,
                                                     int* __restrict__ flag,
                                                     int twoE) {
    __shared__ int any;
    if (threadIdx.x == 0) any = 0;
    __syncthreads();
    int idx = 2 * (int)threadIdx.x + 1;
    if (idx < twoE && ei[idx] != 0) atomicOr(&any, 1);
    __syncthreads();
    if (threadIdx.x == 0) *flag = any;   // 1 => int32, 0 => int64
}

__global__ __launch_bounds__(256) void convert_edges(const int* __restrict__ ei,
                                                     const int* __restrict__ flag,
                                                     int* __restrict__ srcA,
                                                     int* __restrict__ dstA,
                                                     int E, int Et) {
    int e = blockIdx.x * 256 + threadIdx.x;
    if (e >= Et) return;
    int s, d;
    if (e < E) {
        if (*flag) { s = ei[e];      d = ei[E + e]; }          // int32 layout
        else       { s = ei[2 * e];  d = ei[2 * (E + e)]; }    // int64 low words
    } else {
        s = d = e - E;  // self loop
    }
    srcA[e] = s;
    dstA[e] = d;
}

// --- CSR build -------------------------------------------------------------
__global__ __launch_bounds__(256) void count_deg(const int* __restrict__ dstA,
                                                 int* __restrict__ deg, int Et) {
    int e = blockIdx.x * 256 + threadIdx.x;
    if (e < Et) atomicAdd(&deg[dstA[e]], 1);
}

__global__ __launch_bounds__(256) void scan1(const int* __restrict__ deg,
                                             int* __restrict__ rowptr,
                                             int* __restrict__ bsum, int N) {
    __shared__ int tsum[256];
    int chunk0 = blockIdx.x * CHUNK;
    int t = threadIdx.x;
    int vals[8];
    int s = 0;
    #pragma unroll
    for (int i = 0; i < 8; ++i) {
        int idx = chunk0 + t * 8 + i;
        int v = (idx < N) ? deg[idx] : 0;
        vals[i] = s;
        s += v;
    }
    tsum[t] = s;
    __syncthreads();
    for (int off = 1; off < 256; off <<= 1) {
        int v = (t >= off) ? tsum[t - off] : 0;
        __syncthreads();
        tsum[t] += v;
        __syncthreads();
    }
    int texcl = (t > 0) ? tsum[t - 1] : 0;
    #pragma unroll
    for (int i = 0; i < 8; ++i) {
        int idx = chunk0 + t * 8 + i;
        if (idx < N) rowptr[idx] = texcl + vals[i];
    }
    if (t == 255) bsum[blockIdx.x] = tsum[255];
}

__global__ void scan2(int* __restrict__ bsum, int* __restrict__ rowptr,
                      int NB, int N) {
    if (threadIdx.x == 0 && blockIdx.x == 0) {
        int s = 0;
        for (int b = 0; b < NB; ++b) { int v = bsum[b]; bsum[b] = s; s += v; }
        rowptr[N] = s;
    }
}

__global__ __launch_bounds__(256) void scan3(int* __restrict__ rowptr,
                                             const int* __restrict__ bsum,
                                             int* __restrict__ cursor, int N) {
    int idx = blockIdx.x * 256 + threadIdx.x;
    if (idx < N) {
        int v = rowptr[idx] + bsum[idx / CHUNK];
        rowptr[idx] = v;
        cursor[idx] = v;
    }
}

__global__ __launch_bounds__(256) void scatter_edges(const int* __restrict__ srcA,
                                                     const int* __restrict__ dstA,
                                                     int* __restrict__ cursor,
                                                     int* __restrict__ csr_src,
                                                     int Et) {
    int e = blockIdx.x * 256 + threadIdx.x;
    if (e < Et) {
        int pos = atomicAdd(&cursor[dstA[e]], 1);
        csr_src[pos] = srcA[e];
    }
}

// --- register-tiled GEMM: Y[N,M] = act(X[N,K] @ W[K,M] + bias) -------------
// 256 threads. TX = M/8 col-groups, TY = 256/TX row-groups, ROWS = TY*8 rows
// per block. Thread computes 8 rows x 8 cols (cols tx*4..+4 and M/2+tx*4..+4).
// X staged k-major (transposed, +4 pad -> <=2-way banks), W chunk row-major.
template <int M, int K, int ACT>
__global__ __launch_bounds__(256) void gemm_rt(const float* __restrict__ X,
                                               const float* __restrict__ W,
                                               const float* __restrict__ bias,
                                               float* __restrict__ Y,
                                               int N) {
    constexpr int TX   = M / 8;        // 16 (M=128) or 8 (M=64)
    constexpr int ROWS = (256 / TX) * 8;  // 128 or 256
    constexpr int KB   = 16;
    __shared__ float Xt[KB][ROWS + 4];
    __shared__ float Wc[KB][M];

    int tid = threadIdx.x;
    int tx = tid % TX;
    int ty = tid / TX;
    int row0 = blockIdx.x * ROWS;

    float acc[8][8];
    #pragma unroll
    for (int i = 0; i < 8; ++i)
        #pragma unroll
        for (int j = 0; j < 8; ++j) acc[i][j] = 0.f;

    // staging index precompute
    int lr = tid / 4;            // row within tile (step 64)
    int kq = (tid % 4) * 4;      // k quad
    constexpr int WMG = M / 4;   // m-groups for W staging
    int wm = (tid % WMG) * 4;
    int wk = tid / WMG;          // step 256/WMG
    constexpr int WKS = 256 / WMG;

    for (int kc = 0; kc < K; kc += KB) {
        // stage X chunk transposed
        #pragma unroll
        for (int r = lr; r < ROWS; r += 64) {
            int gr = row0 + r;
            float4 xv = make_float4(0.f, 0.f, 0.f, 0.f);
            if (gr < N) xv = *(const float4*)&X[(size_t)gr * K + kc + kq];
            Xt[kq + 0][r] = xv.x;
            Xt[kq + 1][r] = xv.y;
            Xt[kq + 2][r] = xv.z;
            Xt[kq + 3][r] = xv.w;
        }
        // stage W chunk
        #pragma unroll
        for (int k = wk; k < KB; k += WKS) {
            *(float4*)&Wc[k][wm] = *(const float4*)&W[(size_t)(kc + k) * M + wm];
        }
        __syncthreads();

        #pragma unroll
        for (int k = 0; k < KB; ++k) {
            float4 x0 = *(const float4*)&Xt[k][ty * 8];
            float4 x1 = *(const float4*)&Xt[k][ty * 8 + 4];
            float4 w0 = *(const float4*)&Wc[k][tx * 4];
            float4 w1 = *(const float4*)&Wc[k][tx * 4 + M / 2];
            float xs[8] = {x0.x, x0.y, x0.z, x0.w, x1.x, x1.y, x1.z, x1.w};
            float ws[8] = {w0.x, w0.y, w0.z, w0.w, w1.x, w1.y, w1.z, w1.w};
            #pragma unroll
            for (int i = 0; i < 8; ++i)
                #pragma unroll
                for (int j = 0; j < 8; ++j)
                    acc[i][j] = fmaf(xs[i], ws[j], acc[i][j]);
        }
        __syncthreads();
    }

    float4 b0 = *(const float4*)&bias[tx * 4];
    float4 b1 = *(const float4*)&bias[tx * 4 + M / 2];
    float bs[8] = {b0.x, b0.y, b0.z, b0.w, b1.x, b1.y, b1.z, b1.w};
    #pragma unroll
    for (int i = 0; i < 8; ++i) {
        int gr = row0 + ty * 8 + i;
        if (gr >= N) continue;
        float v[8];
        #pragma unroll
        for (int j = 0; j < 8; ++j) {
            float t = acc[i][j] + bs[j];
            if (ACT) t = t > 0.f ? t : expm1f(t);
            v[j] = t;
        }
        *(float4*)&Y[(size_t)gr * M + tx * 4] = make_float4(v[0], v[1], v[2], v[3]);
        *(float4*)&Y[(size_t)gr * M + tx * 4 + M / 2] = make_float4(v[4], v[5], v[6], v[7]);
    }
}

// --- fused GATv2 aggregate: online softmax over CSR in-edges ---------------
template <int H, int C>
__global__ __launch_bounds__(256) void gat_agg(const float* __restrict__ xl,
                                               const float* __restrict__ xr,
                                               const float* __restrict__ att,
                                               const int* __restrict__ rowptr,
                                               const int* __restrict__ csr_src,
                                               const float* __restrict__ bias,
                                               float* __restrict__ outv,
                                               int N) {
    constexpr int HC  = H * C;
    constexpr int CPL = HC / 64;   // 2 for layer1, 1 for layer2
    constexpr int G   = C / CPL;   // lanes per head group (8 or 64)
    int wave = threadIdx.x >> 6;
    int lane = threadIdx.x & 63;
    int node = blockIdx.x * 4 + wave;
    if (node >= N) return;
    int c0 = lane * CPL;

    float a0 = att[c0];
    float xr0 = xr[(size_t)node * HC + c0];
    float a1 = 0.f, xr1v = 0.f;
    if constexpr (CPL == 2) {
        a1 = att[c0 + 1];
        xr1v = xr[(size_t)node * HC + c0 + 1];
    }

    float m = -INFINITY, dsum = 0.f, acc0 = 0.f, acc1 = 0.f;
    int start = rowptr[node], end = rowptr[node + 1];

    for (int base = start; base < end; base += 64) {
        int nbatch = min(64, end - base);
        int sreg = (base + lane < end) ? csr_src[base + lane] : 0;
        for (int k = 0; k < nbatch; ++k) {
            int s = __shfl(sreg, k, 64);
            float x0, x1v = 0.f;
            if constexpr (CPL == 2) {
                float2 xv = *(const float2*)&xl[(size_t)s * HC + c0];
                x0 = xv.x; x1v = xv.y;
            } else {
                x0 = xl[(size_t)s * HC + c0];
            }
            float t0 = x0 + xr0;
            t0 = t0 > 0.f ? t0 : NEG_SLOPE * t0;
            float part = t0 * a0;
            if constexpr (CPL == 2) {
                float t1 = x1v + xr1v;
                t1 = t1 > 0.f ? t1 : NEG_SLOPE * t1;
                part += t1 * a1;
            }
            #pragma unroll
            for (int off = 1; off < G; off <<= 1)
                part += __shfl_xor(part, off, 64);
            float mnew = fmaxf(m, part);
            float alpha = __expf(m - mnew);
            float p = __expf(part - mnew);
            dsum = dsum * alpha + p;
            acc0 = acc0 * alpha + p * x0;
            if constexpr (CPL == 2) acc1 = acc1 * alpha + p * x1v;
            m = mnew;
        }
    }

    float inv = 1.f / dsum;
    float v0 = acc0 * inv + bias[c0];
    v0 = v0 > 0.f ? v0 : expm1f(v0);
    outv[(size_t)node * HC + c0] = v0;
    if constexpr (CPL == 2) {
        float v1 = acc1 * inv + bias[c0 + 1];
        v1 = v1 > 0.f ? v1 : expm1f(v1);
        outv[(size_t)node * HC + c0 + 1] = v1;
    }
}

extern "C" void kernel_launch(void* const* d_in, const int* in_sizes, int n_in,
                              void* d_out, int out_size, void* d_ws, size_t ws_size,
                              hipStream_t stream) {
    const float* x    = (const float*)d_in[0];
    const int*   ei   = (const int*)d_in[1];
    const float* Wl1  = (const float*)d_in[2];
    const float* bl1  = (const float*)d_in[3];
    const float* Wr1  = (const float*)d_in[4];
    const float* br1  = (const float*)d_in[5];
    const float* att1 = (const float*)d_in[6];
    const float* bias1= (const float*)d_in[7];
    const float* Wl2  = (const float*)d_in[8];
    const float* bl2  = (const float*)d_in[9];
    const float* Wr2  = (const float*)d_in[10];
    const float* br2  = (const float*)d_in[11];
    const float* att2 = (const float*)d_in[12];
    const float* bias2= (const float*)d_in[13];
    const float* Wlin = (const float*)d_in[14];
    const float* blin = (const float*)d_in[15];
    float* out = (float*)d_out;

    const int F = 128;
    int N  = in_sizes[0] / F;        // 50000
    int E  = in_sizes[1] / 2;        // 800000
    int Et = E + N;                  // + self loops

    // workspace layout
    float* xl1 = (float*)d_ws;            // N*128; reused: xl2, xr2 (N*64 each)
    float* xr1 = xl1 + (size_t)N * 128;   // N*128; reused: h2 (N*64)
    float* h1  = xr1 + (size_t)N * 128;   // N*128
    int* srcA   = (int*)(h1 + (size_t)N * 128);
    int* dstA   = srcA + Et;
    int* deg    = dstA + Et;              // N
    int* rowptr = deg + N;                // N+1
    int* cursor = rowptr + N + 1;         // N
    int* csr_src= cursor + N;             // Et
    int* fl     = csr_src + Et;
    int* bsum   = fl + 1;                 // <=32

    float* xl2 = xl1;
    float* xr2 = xl1 + (size_t)N * 64;
    float* h2  = xr1;

    auto cdiv = [](long a, long b) { return (int)((a + b - 1) / b); };
    int NB = cdiv(N, CHUNK);

    // edge normalization + CSR build (shared by both layers)
    detect_kernel<<<1, 256, 0, stream>>>(ei, fl, 2 * E);
    convert_edges<<<cdiv(Et, 256), 256, 0, stream>>>(ei, fl, srcA, dstA, E, Et);
    hipMemsetAsync(deg, 0, (size_t)N * 4, stream);
    count_deg<<<cdiv(Et, 256), 256, 0, stream>>>(dstA, deg, Et);
    scan1<<<NB, 256, 0, stream>>>(deg, rowptr, bsum, N);
    scan2<<<1, 64, 0, stream>>>(bsum, rowptr, NB, N);
    scan3<<<cdiv(N, 256), 256, 0, stream>>>(rowptr, bsum, cursor, N);
    scatter_edges<<<cdiv(Et, 256), 256, 0, stream>>>(srcA, dstA, cursor, csr_src, Et);

    // ---- layer 1 (H=8, C=16, concat) ----
    gemm_rt<128, 128, 0><<<cdiv(N, 128), 256, 0, stream>>>(x, Wl1, bl1, xl1, N);
    gemm_rt<128, 128, 0><<<cdiv(N, 128), 256, 0, stream>>>(x, Wr1, br1, xr1, N);
    gat_agg<8, 16><<<cdiv(N, 4), 256, 0, stream>>>(
        xl1, xr1, att1, rowptr, csr_src, bias1, h1, N);

    // ---- layer 2 (H=1, C=64) ----
    gemm_rt<64, 128, 0><<<cdiv(N, 256), 256, 0, stream>>>(h1, Wl2, bl2, xl2, N);
    gemm_rt<64, 128, 0><<<cdiv(N, 256), 256, 0, stream>>>(h1, Wr2, br2, xr2, N);
    gat_agg<1, 64><<<cdiv(N, 4), 256, 0, stream>>>(
        xl2, xr2, att2, rowptr, csr_src, bias2, h2, N);

    // ---- final linear + ELU -> d_out ----
    gemm_rt<128, 64, 1><<<cdiv(N, 128), 256, 0, stream>>>(h2, Wlin, blin, out, N);
}